// Round 1
// baseline (1042.002 us; speedup 1.0000x reference)
//
#include <hip/hip_runtime.h>

#define N_NODES 100000
#define N_EDGES 1600000
#define T_STEPS 6
#define FDIM    64
#define OUT2    16
#define C2      0.01f

// One wave per edge-iteration, lane = feature. Coalesced 256B gather of
// feat[src], 64 contiguous f32 atomics into sums[(t*N+dst)*64 + lane].
// cnt (optional) accumulated by lane 0 only.
__global__ __launch_bounds__(256) void k_scatter(
    const float* __restrict__ feat, const int* __restrict__ src,
    const int* __restrict__ dst, const int* __restrict__ tix,
    float* __restrict__ sums, float* __restrict__ cnt)
{
  const int lane = threadIdx.x & 63;
  int w = blockIdx.x * (blockDim.x >> 6) + (threadIdx.x >> 6);
  const int nw = gridDim.x * (blockDim.x >> 6);
  for (int e = w; e < N_EDGES; e += nw) {
    const int s = src[e];
    const int d = dst[e];
    const int t = tix[e];
    const float v = feat[(size_t)s * FDIM + lane];
    atomicAdd(sums + ((size_t)t * N_NODES + d) * FDIM + lane, v);
    if (cnt != nullptr && lane == 0)
      atomicAdd(cnt + (size_t)t * N_NODES + d, 1.0f);
  }
}

// lane = node. Pass A: per-(t,node) scale sc = (1/clip(cnt,1)) / (1 - c^2*||mean||^2).
// Pass B: y[j] = relu(b[j] + sum_{t,f} sums[t,n,f]*sc[t] * W[(t*64+f)*OUTF + j]).
// W addresses are wave-uniform -> scalar loads; acc[OUTF] lives in VGPRs.
template <int OUTF>
__global__ __launch_bounds__(64) void k_fused_gemm(
    const float* __restrict__ sums, const float* __restrict__ cnt,
    const float* __restrict__ W, const float* __restrict__ bias,
    float* __restrict__ out)
{
  int n = blockIdx.x * 64 + threadIdx.x;
  const bool valid = (n < N_NODES);
  if (!valid) n = N_NODES - 1;

  // ---- pass A: scale factors per t ----
  float sc0, sc1, sc2, sc3, sc4, sc5;
  #pragma unroll
  for (int t = 0; t < T_STEPS; ++t) {
    const float c  = cnt[(size_t)t * N_NODES + n];
    const float rc = 1.0f / fmaxf(c, 1.0f);
    const float4* row = (const float4*)(sums + ((size_t)t * N_NODES + n) * FDIM);
    float ss = 0.0f;
    #pragma unroll 1
    for (int q = 0; q < FDIM / 4; ++q) {
      float4 v = row[q];
      float m0 = v.x * rc, m1 = v.y * rc, m2 = v.z * rc, m3 = v.w * rc;
      ss += m0 * m0 + m1 * m1 + m2 * m2 + m3 * m3;
    }
    const float norm = 1.0f - C2 * ss;
    const float s = rc / norm;
    if (t == 0) sc0 = s; else if (t == 1) sc1 = s; else if (t == 2) sc2 = s;
    else if (t == 3) sc3 = s; else if (t == 4) sc4 = s; else sc5 = s;
  }

  // ---- pass B: dense layer ----
  float acc[OUTF];
  #pragma unroll
  for (int j = 0; j < OUTF; ++j) acc[j] = bias[j];

  #pragma unroll 1
  for (int t = 0; t < T_STEPS; ++t) {
    const float s = (t == 0) ? sc0 : (t == 1) ? sc1 : (t == 2) ? sc2
                  : (t == 3) ? sc3 : (t == 4) ? sc4 : sc5;
    const float4* row = (const float4*)(sums + ((size_t)t * N_NODES + n) * FDIM);
    #pragma unroll 1
    for (int q8 = 0; q8 < FDIM / 8; ++q8) {
      const float4 a = row[q8 * 2 + 0];
      const float4 b4 = row[q8 * 2 + 1];
      const float hv[8] = {a.x, a.y, a.z, a.w, b4.x, b4.y, b4.z, b4.w};
      const float* wr = W + ((size_t)t * FDIM + q8 * 8) * OUTF;
      #pragma unroll
      for (int i = 0; i < 8; ++i) {
        const float hs = hv[i] * s;
        #pragma unroll
        for (int j = 0; j < OUTF; ++j)
          acc[j] = fmaf(hs, wr[i * OUTF + j], acc[j]);
      }
    }
  }

  if (valid) {
    float* o = out + (size_t)n * OUTF;
    #pragma unroll
    for (int j = 0; j < OUTF; ++j) o[j] = fmaxf(acc[j], 0.0f);
  }
}

extern "C" void kernel_launch(void* const* d_in, const int* in_sizes, int n_in,
                              void* d_out, int out_size, void* d_ws, size_t ws_size,
                              hipStream_t stream) {
  const float* x  = (const float*)d_in[0];
  const int*  ei  = (const int*)d_in[1];
  const int*  tix = (const int*)d_in[2];
  const float* W1 = (const float*)d_in[3];
  const float* b1 = (const float*)d_in[4];
  const float* W2 = (const float*)d_in[5];
  const float* b2 = (const float*)d_in[6];
  float* out = (float*)d_out;

  const int* src = ei;
  const int* dst = ei + N_EDGES;

  float* sums = (float*)d_ws;
  float* cnt  = sums + (size_t)T_STEPS * N_NODES * FDIM;
  float* h1   = cnt + (size_t)T_STEPS * N_NODES;

  const size_t sums_bytes = (size_t)T_STEPS * N_NODES * FDIM * sizeof(float);
  const size_t cnt_bytes  = (size_t)T_STEPS * N_NODES * sizeof(float);

  const int gemm_grid = (N_NODES + 63) / 64;

  // Layer 1
  hipMemsetAsync(sums, 0, sums_bytes + cnt_bytes, stream);  // sums + cnt contiguous
  k_scatter<<<2048, 256, 0, stream>>>(x, src, dst, tix, sums, cnt);
  k_fused_gemm<64><<<gemm_grid, 64, 0, stream>>>(sums, cnt, W1, b1, h1);

  // Layer 2 (cnt is identical across layers -> reuse)
  hipMemsetAsync(sums, 0, sums_bytes, stream);
  k_scatter<<<2048, 256, 0, stream>>>(h1, src, dst, tix, sums, (float*)nullptr);
  k_fused_gemm<16><<<gemm_grid, 64, 0, stream>>>(sums, cnt, W2, b2, out);
}

// Round 5
// 779.311 us; speedup vs baseline: 1.3371x; 1.3371x over previous
//
#include <hip/hip_runtime.h>

#define N_NODES 100000
#define N_EDGES 1600000
#define T_STEPS 6
#define FDIM    64
#define SEG     (T_STEPS * N_NODES)
#define C2      0.01f

// Build per-(t,dst)-segment linked lists over edges. One atomicExch per edge
// on the 2.4MB head array (L2-resident) -- replaces round 1's 102M f32 atomics.
__global__ __launch_bounds__(256) void k_build(
    const int* __restrict__ dst, const int* __restrict__ tix,
    int* __restrict__ head, int* __restrict__ nxt)
{
  const int e = blockIdx.x * blockDim.x + threadIdx.x;
  if (e >= N_EDGES) return;
  const int key = tix[e] * N_NODES + dst[e];
  nxt[e] = atomicExch(&head[key], e);
}

// One wave per (t,dst) segment, lane = feature. Walk the edge list, f32-sum
// the gathered 256B rows, write RAW sums + cnt (no normalization here --
// the normalization arithmetic lives in k_fused_gemm, bit-identical to the
// round-1 pipeline that passed at absmax 128). Edge-sum order differs from
// round 1's random atomic order, which round 1 proved is tolerated.
__global__ __launch_bounds__(256) void k_sum(
    const float* __restrict__ feat, const int* __restrict__ src,
    const int* __restrict__ head, const int* __restrict__ nxt,
    float* __restrict__ sums, float* __restrict__ cnt)
{
  const int lane = threadIdx.x & 63;
  const int seg = blockIdx.x * (blockDim.x >> 6) + (threadIdx.x >> 6);
  if (seg >= SEG) return;

  float v = 0.0f;
  int c = 0;
  int e = head[seg];
  while (e >= 0) {
    v += feat[(size_t)src[e] * FDIM + lane];
    ++c;
    e = nxt[e];
  }
  sums[(size_t)seg * FDIM + lane] = v;
  if (lane == 0) cnt[seg] = (float)c;
}

// ===== VERBATIM round-1 kernel (passed, absmax 128) -- do not touch. =====
// lane = node. Pass A: per-(t,node) scale sc = (1/clip(cnt,1)) / (1 - c^2*||mean||^2).
// Pass B: y[j] = relu(b[j] + sum_{t,f} sums[t,n,f]*sc[t] * W[(t*64+f)*OUTF + j]).
// W addresses are wave-uniform -> scalar loads; acc[OUTF] lives in VGPRs.
template <int OUTF>
__global__ __launch_bounds__(64) void k_fused_gemm(
    const float* __restrict__ sums, const float* __restrict__ cnt,
    const float* __restrict__ W, const float* __restrict__ bias,
    float* __restrict__ out)
{
  int n = blockIdx.x * 64 + threadIdx.x;
  const bool valid = (n < N_NODES);
  if (!valid) n = N_NODES - 1;

  // ---- pass A: scale factors per t ----
  float sc0, sc1, sc2, sc3, sc4, sc5;
  #pragma unroll
  for (int t = 0; t < T_STEPS; ++t) {
    const float c  = cnt[(size_t)t * N_NODES + n];
    const float rc = 1.0f / fmaxf(c, 1.0f);
    const float4* row = (const float4*)(sums + ((size_t)t * N_NODES + n) * FDIM);
    float ss = 0.0f;
    #pragma unroll 1
    for (int q = 0; q < FDIM / 4; ++q) {
      float4 v = row[q];
      float m0 = v.x * rc, m1 = v.y * rc, m2 = v.z * rc, m3 = v.w * rc;
      ss += m0 * m0 + m1 * m1 + m2 * m2 + m3 * m3;
    }
    const float norm = 1.0f - C2 * ss;
    const float s = rc / norm;
    if (t == 0) sc0 = s; else if (t == 1) sc1 = s; else if (t == 2) sc2 = s;
    else if (t == 3) sc3 = s; else if (t == 4) sc4 = s; else sc5 = s;
  }

  // ---- pass B: dense layer ----
  float acc[OUTF];
  #pragma unroll
  for (int j = 0; j < OUTF; ++j) acc[j] = bias[j];

  #pragma unroll 1
  for (int t = 0; t < T_STEPS; ++t) {
    const float s = (t == 0) ? sc0 : (t == 1) ? sc1 : (t == 2) ? sc2
                  : (t == 3) ? sc3 : (t == 4) ? sc4 : sc5;
    const float4* row = (const float4*)(sums + ((size_t)t * N_NODES + n) * FDIM);
    #pragma unroll 1
    for (int q8 = 0; q8 < FDIM / 8; ++q8) {
      const float4 a = row[q8 * 2 + 0];
      const float4 b4 = row[q8 * 2 + 1];
      const float hv[8] = {a.x, a.y, a.z, a.w, b4.x, b4.y, b4.z, b4.w};
      const float* wr = W + ((size_t)t * FDIM + q8 * 8) * OUTF;
      #pragma unroll
      for (int i = 0; i < 8; ++i) {
        const float hs = hv[i] * s;
        #pragma unroll
        for (int j = 0; j < OUTF; ++j)
          acc[j] = fmaf(hs, wr[i * OUTF + j], acc[j]);
      }
    }
  }

  if (valid) {
    float* o = out + (size_t)n * OUTF;
    #pragma unroll
    for (int j = 0; j < OUTF; ++j) o[j] = fmaxf(acc[j], 0.0f);
  }
}
// ===== end verbatim round-1 kernel =====

extern "C" void kernel_launch(void* const* d_in, const int* in_sizes, int n_in,
                              void* d_out, int out_size, void* d_ws, size_t ws_size,
                              hipStream_t stream) {
  const float* x  = (const float*)d_in[0];
  const int*  ei  = (const int*)d_in[1];
  const int*  tix = (const int*)d_in[2];
  const float* W1 = (const float*)d_in[3];
  const float* b1 = (const float*)d_in[4];
  const float* W2 = (const float*)d_in[5];
  const float* b2 = (const float*)d_in[6];

  const int* src = ei;
  const int* dst = ei + N_EDGES;

  // Workspace: head[SEG] | nxt[NE] | sums[SEG*64] | cnt[SEG] | h1[NN*64]
  // (head+nxt = 2.2M ints -> sums offset 8.8MB, 16B-aligned for float4 loads)
  int*   head = (int*)d_ws;
  int*   nxt  = head + SEG;
  float* sums = (float*)(nxt + N_EDGES);
  float* cnt  = sums + (size_t)SEG * FDIM;
  float* h1   = cnt + SEG;

  const int gemm_grid = (N_NODES + 63) / 64;
  const int seg_grid  = (SEG + 3) / 4;

  hipMemsetAsync(head, 0xFF, (size_t)SEG * sizeof(int), stream);
  k_build<<<(N_EDGES + 255) / 256, 256, 0, stream>>>(dst, tix, head, nxt);

  // Layer 1
  k_sum<<<seg_grid, 256, 0, stream>>>(x, src, head, nxt, sums, cnt);
  k_fused_gemm<64><<<gemm_grid, 64, 0, stream>>>(sums, cnt, W1, b1, h1);

  // Layer 2 (same edge lists; cnt identical but rewritten -- harmless)
  k_sum<<<seg_grid, 256, 0, stream>>>(h1, src, head, nxt, sums, cnt);
  k_fused_gemm<16><<<gemm_grid, 64, 0, stream>>>(sums, cnt, W2, b2, (float*)d_out);
}

// Round 6
// 692.931 us; speedup vs baseline: 1.5038x; 1.1247x over previous
//
#include <hip/hip_runtime.h>

#define N_NODES 100000
#define N_EDGES 1600000
#define T_STEPS 6
#define FDIM    64
#define SEG     (T_STEPS * N_NODES)
#define C2      0.01f

// Build per-(t,dst)-segment linked lists over edges. One atomicExch per edge
// on the 2.4MB head array (L2-resident).
__global__ __launch_bounds__(256) void k_build(
    const int* __restrict__ dst, const int* __restrict__ tix,
    int* __restrict__ head, int* __restrict__ nxt)
{
  const int e = blockIdx.x * blockDim.x + threadIdx.x;
  if (e >= N_EDGES) return;
  const int key = tix[e] * N_NODES + dst[e];
  nxt[e] = atomicExch(&head[key], e);
}

// One wave per NODE, lane = feature. Walk the node's 6 per-t edge lists
// CONCURRENTLY: 6 independent dependent-chains per wave -> ~6x memory-level
// parallelism vs round-5's one-chain-per-wave (which was latency-bound:
// 28% BW, 18% VALU). Per-segment visit order is the SAME list order as
// round 5, so sums/cnt are bit-identical -> zero absmax risk.
__global__ __launch_bounds__(256) void k_sum6(
    const float* __restrict__ feat, const int* __restrict__ src,
    const int* __restrict__ head, const int* __restrict__ nxt,
    float* __restrict__ sums, float* __restrict__ cnt)
{
  const int lane = threadIdx.x & 63;
  const int n = blockIdx.x * (blockDim.x >> 6) + (threadIdx.x >> 6);
  if (n >= N_NODES) return;

  int e0 = head[(size_t)0 * N_NODES + n];
  int e1 = head[(size_t)1 * N_NODES + n];
  int e2 = head[(size_t)2 * N_NODES + n];
  int e3 = head[(size_t)3 * N_NODES + n];
  int e4 = head[(size_t)4 * N_NODES + n];
  int e5 = head[(size_t)5 * N_NODES + n];

  float v0 = 0.f, v1 = 0.f, v2 = 0.f, v3 = 0.f, v4 = 0.f, v5 = 0.f;
  int c0 = 0, c1 = 0, c2 = 0, c3 = 0, c4 = 0, c5 = 0;

  while ((e0 >= 0) | (e1 >= 0) | (e2 >= 0) | (e3 >= 0) | (e4 >= 0) | (e5 >= 0)) {
    if (e0 >= 0) { v0 += feat[(size_t)src[e0] * FDIM + lane]; ++c0; e0 = nxt[e0]; }
    if (e1 >= 0) { v1 += feat[(size_t)src[e1] * FDIM + lane]; ++c1; e1 = nxt[e1]; }
    if (e2 >= 0) { v2 += feat[(size_t)src[e2] * FDIM + lane]; ++c2; e2 = nxt[e2]; }
    if (e3 >= 0) { v3 += feat[(size_t)src[e3] * FDIM + lane]; ++c3; e3 = nxt[e3]; }
    if (e4 >= 0) { v4 += feat[(size_t)src[e4] * FDIM + lane]; ++c4; e4 = nxt[e4]; }
    if (e5 >= 0) { v5 += feat[(size_t)src[e5] * FDIM + lane]; ++c5; e5 = nxt[e5]; }
  }

  sums[((size_t)0 * N_NODES + n) * FDIM + lane] = v0;
  sums[((size_t)1 * N_NODES + n) * FDIM + lane] = v1;
  sums[((size_t)2 * N_NODES + n) * FDIM + lane] = v2;
  sums[((size_t)3 * N_NODES + n) * FDIM + lane] = v3;
  sums[((size_t)4 * N_NODES + n) * FDIM + lane] = v4;
  sums[((size_t)5 * N_NODES + n) * FDIM + lane] = v5;
  if (lane == 0) {
    cnt[(size_t)0 * N_NODES + n] = (float)c0;
    cnt[(size_t)1 * N_NODES + n] = (float)c1;
    cnt[(size_t)2 * N_NODES + n] = (float)c2;
    cnt[(size_t)3 * N_NODES + n] = (float)c3;
    cnt[(size_t)4 * N_NODES + n] = (float)c4;
    cnt[(size_t)5 * N_NODES + n] = (float)c5;
  }
}

// ===== VERBATIM round-1 kernel (passed, absmax 128) -- do not touch. =====
template <int OUTF>
__global__ __launch_bounds__(64) void k_fused_gemm(
    const float* __restrict__ sums, const float* __restrict__ cnt,
    const float* __restrict__ W, const float* __restrict__ bias,
    float* __restrict__ out)
{
  int n = blockIdx.x * 64 + threadIdx.x;
  const bool valid = (n < N_NODES);
  if (!valid) n = N_NODES - 1;

  // ---- pass A: scale factors per t ----
  float sc0, sc1, sc2, sc3, sc4, sc5;
  #pragma unroll
  for (int t = 0; t < T_STEPS; ++t) {
    const float c  = cnt[(size_t)t * N_NODES + n];
    const float rc = 1.0f / fmaxf(c, 1.0f);
    const float4* row = (const float4*)(sums + ((size_t)t * N_NODES + n) * FDIM);
    float ss = 0.0f;
    #pragma unroll 1
    for (int q = 0; q < FDIM / 4; ++q) {
      float4 v = row[q];
      float m0 = v.x * rc, m1 = v.y * rc, m2 = v.z * rc, m3 = v.w * rc;
      ss += m0 * m0 + m1 * m1 + m2 * m2 + m3 * m3;
    }
    const float norm = 1.0f - C2 * ss;
    const float s = rc / norm;
    if (t == 0) sc0 = s; else if (t == 1) sc1 = s; else if (t == 2) sc2 = s;
    else if (t == 3) sc3 = s; else if (t == 4) sc4 = s; else sc5 = s;
  }

  // ---- pass B: dense layer ----
  float acc[OUTF];
  #pragma unroll
  for (int j = 0; j < OUTF; ++j) acc[j] = bias[j];

  #pragma unroll 1
  for (int t = 0; t < T_STEPS; ++t) {
    const float s = (t == 0) ? sc0 : (t == 1) ? sc1 : (t == 2) ? sc2
                  : (t == 3) ? sc3 : (t == 4) ? sc4 : sc5;
    const float4* row = (const float4*)(sums + ((size_t)t * N_NODES + n) * FDIM);
    #pragma unroll 1
    for (int q8 = 0; q8 < FDIM / 8; ++q8) {
      const float4 a = row[q8 * 2 + 0];
      const float4 b4 = row[q8 * 2 + 1];
      const float hv[8] = {a.x, a.y, a.z, a.w, b4.x, b4.y, b4.z, b4.w};
      const float* wr = W + ((size_t)t * FDIM + q8 * 8) * OUTF;
      #pragma unroll
      for (int i = 0; i < 8; ++i) {
        const float hs = hv[i] * s;
        #pragma unroll
        for (int j = 0; j < OUTF; ++j)
          acc[j] = fmaf(hs, wr[i * OUTF + j], acc[j]);
      }
    }
  }

  if (valid) {
    float* o = out + (size_t)n * OUTF;
    #pragma unroll
    for (int j = 0; j < OUTF; ++j) o[j] = fmaxf(acc[j], 0.0f);
  }
}
// ===== end verbatim round-1 kernel =====

extern "C" void kernel_launch(void* const* d_in, const int* in_sizes, int n_in,
                              void* d_out, int out_size, void* d_ws, size_t ws_size,
                              hipStream_t stream) {
  const float* x  = (const float*)d_in[0];
  const int*  ei  = (const int*)d_in[1];
  const int*  tix = (const int*)d_in[2];
  const float* W1 = (const float*)d_in[3];
  const float* b1 = (const float*)d_in[4];
  const float* W2 = (const float*)d_in[5];
  const float* b2 = (const float*)d_in[6];

  const int* src = ei;
  const int* dst = ei + N_EDGES;

  // Workspace: head[SEG] | nxt[NE] | sums[SEG*64] | cnt[SEG] | h1[NN*64]  (~190.4 MB)
  int*   head = (int*)d_ws;
  int*   nxt  = head + SEG;
  float* sums = (float*)(nxt + N_EDGES);
  float* cnt  = sums + (size_t)SEG * FDIM;
  float* h1   = cnt + SEG;

  const int gemm_grid = (N_NODES + 63) / 64;
  const int node_grid = (N_NODES + 3) / 4;   // 4 waves/block, wave per node

  hipMemsetAsync(head, 0xFF, (size_t)SEG * sizeof(int), stream);
  k_build<<<(N_EDGES + 255) / 256, 256, 0, stream>>>(dst, tix, head, nxt);

  // Layer 1
  k_sum6<<<node_grid, 256, 0, stream>>>(x, src, head, nxt, sums, cnt);
  k_fused_gemm<64><<<gemm_grid, 64, 0, stream>>>(sums, cnt, W1, b1, h1);

  // Layer 2 (same edge lists; cnt identical but rewritten -- harmless)
  k_sum6<<<node_grid, 256, 0, stream>>>(h1, src, head, nxt, sums, cnt);
  k_fused_gemm<16><<<gemm_grid, 64, 0, stream>>>(sums, cnt, W2, b2, (float*)d_out);
}